// Round 7
// baseline (1737.891 us; speedup 1.0000x reference)
//
#include <hip/hip_runtime.h>

#define NN 2000000
#define DD 128
#define BB 1024
#define STEPS 3
#define SPLIT 8          // blocks per graph in att_partial
#define PSTRIDE 132      // floats per partial: [0]=m, [1]=s, [4..131]=r

// ---------------- prep: transpose weights + combine bias (runs once) --------
// WT[k][j] (k in [0,384), j in [0,512)):
//   k <  256: W_ih[j][k]      (W_ih is [512,256] row-major)
//   k >= 256: W_hh[j][k-256]  (W_hh is [512,128] row-major)
__global__ void prep_kernel(const float* __restrict__ W_ih,
                            const float* __restrict__ W_hh,
                            const float* __restrict__ b_ih,
                            const float* __restrict__ b_hh,
                            float* __restrict__ WT, float* __restrict__ bias) {
    int idx = blockIdx.x * blockDim.x + threadIdx.x;
    if (idx < 384 * 512) {
        int k = idx >> 9;
        int j = idx & 511;
        WT[idx] = (k < 256) ? W_ih[j * 256 + k] : W_hh[j * 128 + (k - 256)];
    }
    if (idx < 512) bias[idx] = b_ih[idx] + b_hh[idx];
}

// ---------------- segment starts (runs once) --------------------------------
// start[b] = first node index with batch_index >= b ; start[BB] = NN
__global__ void segstart_kernel(const int* __restrict__ bi, int* __restrict__ start) {
    int n = blockIdx.x * blockDim.x + threadIdx.x;
    if (n >= NN) return;
    int v = bi[n];
    int p = (n == 0) ? -1 : bi[n - 1];
    for (int t = p + 1; t <= v; ++t) start[t] = n;
    if (n == NN - 1) {
        for (int t = v + 1; t <= BB; ++t) start[t] = NN;
    }
}

// ---------------- LSTM cell (per step) ---------------------------------------
__device__ __forceinline__ float sigmoid_f(float x) { return 1.0f / (1.0f + __expf(-x)); }
__device__ __forceinline__ float tanh_f(float x) {
    float e = __expf(2.0f * x);
    return 1.0f - 2.0f / (e + 1.0f);   // saturates cleanly, no NaN
}

__launch_bounds__(256)
__global__ void lstm_kernel(const float* __restrict__ q_star,
                            float* __restrict__ h, float* __restrict__ c,
                            const float* __restrict__ WT,
                            const float* __restrict__ bias) {
    __shared__ float in_lds[4][384];
    __shared__ float gate_lds[4][512];
    const int b0 = blockIdx.x * 4;
    const int tid = threadIdx.x;

    for (int idx = tid; idx < 4 * 384; idx += 256) {
        int bb = idx / 384;
        int k = idx - bb * 384;
        in_lds[bb][k] = (k < 256) ? q_star[(b0 + bb) * 256 + k]
                                  : h[(b0 + bb) * 128 + (k - 256)];
    }
    __syncthreads();

    const int j0 = tid, j1 = tid + 256;
    float acc[4][2] = {};
    for (int k = 0; k < 384; k += 4) {
        float4 a0 = *(const float4*)&in_lds[0][k];
        float4 a1 = *(const float4*)&in_lds[1][k];
        float4 a2 = *(const float4*)&in_lds[2][k];
        float4 a3 = *(const float4*)&in_lds[3][k];
        const float* f0 = (const float*)&a0;
        const float* f1 = (const float*)&a1;
        const float* f2 = (const float*)&a2;
        const float* f3 = (const float*)&a3;
#pragma unroll
        for (int kk = 0; kk < 4; ++kk) {
            float w0 = WT[(k + kk) * 512 + j0];
            float w1 = WT[(k + kk) * 512 + j1];
            acc[0][0] = fmaf(f0[kk], w0, acc[0][0]);
            acc[0][1] = fmaf(f0[kk], w1, acc[0][1]);
            acc[1][0] = fmaf(f1[kk], w0, acc[1][0]);
            acc[1][1] = fmaf(f1[kk], w1, acc[1][1]);
            acc[2][0] = fmaf(f2[kk], w0, acc[2][0]);
            acc[2][1] = fmaf(f2[kk], w1, acc[2][1]);
            acc[3][0] = fmaf(f3[kk], w0, acc[3][0]);
            acc[3][1] = fmaf(f3[kk], w1, acc[3][1]);
        }
    }
    float bj0 = bias[j0], bj1 = bias[j1];
#pragma unroll
    for (int bb = 0; bb < 4; ++bb) {
        gate_lds[bb][j0] = acc[bb][0] + bj0;
        gate_lds[bb][j1] = acc[bb][1] + bj1;
    }
    __syncthreads();

#pragma unroll
    for (int it = 0; it < 2; ++it) {
        int item = tid + it * 256;
        int bb = item >> 7;
        int d = item & 127;
        int b = b0 + bb;
        float gi = gate_lds[bb][d];
        float gf = gate_lds[bb][128 + d];
        float gg = gate_lds[bb][256 + d];
        float go = gate_lds[bb][384 + d];
        float cn = sigmoid_f(gf) * c[b * 128 + d] + sigmoid_f(gi) * tanh_f(gg);
        float hn = sigmoid_f(go) * tanh_f(cn);
        c[b * 128 + d] = cn;
        h[b * 128 + d] = hn;
    }
}

// ---------------- attention pass 1: per-chunk partials ------------------------
// SPLIT blocks per graph; block (b, sp) covers a contiguous 1/SPLIT slice of
// graph b's segment. 16 groups of 16 lanes per block; each group runs ONE
// online-softmax stream with depth-1 clamped prefetch. Slim register budget:
// __launch_bounds__(256, 8) pins VGPR<=64 so 8 blocks/CU (32 waves/CU) are
// resident — the occupancy lever this round tests. Every node processed in
// the loop is valid (condition n < a1), so no kill-mask on the current tile;
// only the prefetch index is clamped.
__launch_bounds__(256, 8)
__global__ void att_partial_kernel(const float* __restrict__ x,
                                   const float* __restrict__ h,
                                   const int* __restrict__ start,
                                   float* __restrict__ partials) {
    const int b = blockIdx.x >> 3;        // graph index
    const int sp = blockIdx.x & (SPLIT - 1);
    const int tid = threadIdx.x;
    const int g16 = tid >> 4;     // block-wide group id: 0..15
    const int sl = tid & 15;      // lane within group
    const int c0 = 4 * sl;        // channel base (and 64+c0 for the hi half)

    const int s0 = start[b];
    const int s1 = start[b + 1];
    const int len = s1 - s0;
    const int chunk = (len + SPLIT - 1) >> 3;
    const int a0 = s0 + sp * chunk;
    const int a1 = min(a0 + chunk, s1);

    float4 qlo = *(const float4*)&h[b * 128 + c0];
    float4 qhi = *(const float4*)&h[b * 128 + 64 + c0];

    float m = -1e30f, s = 0.0f;
    float4 rlo = make_float4(0.f, 0.f, 0.f, 0.f);
    float4 rhi = make_float4(0.f, 0.f, 0.f, 0.f);

    if (a0 < a1) {
        const int lastn = a1 - 1;
        const int n0 = a0 + g16;

        int cur = min(n0, lastn);
        float4 xl = *(const float4*)&x[(size_t)cur * 128 + c0];
        float4 xh = *(const float4*)&x[(size_t)cur * 128 + 64 + c0];

        for (int n = n0; n < a1; n += 16) {
            // prefetch next node (clamped index: always a valid row)
            int nxt = min(n + 16, lastn);
            float4 nl = *(const float4*)&x[(size_t)nxt * 128 + c0];
            float4 nh = *(const float4*)&x[(size_t)nxt * 128 + 64 + c0];

            // dot over this group's 16 lanes (128 channels)
            float d = xl.x * qlo.x + xl.y * qlo.y + xl.z * qlo.z + xl.w * qlo.w
                    + xh.x * qhi.x + xh.y * qhi.y + xh.z * qhi.z + xh.w * qhi.w;
#pragma unroll
            for (int off = 8; off >= 1; off >>= 1)
                d += __shfl_xor(d, off, 64);   // offs < 16 stay within the 16-lane group

            // online-softmax update (node n is valid by loop condition)
            float nm = fmaxf(m, d);
            float fac = __expf(m - nm);
            float w = __expf(d - nm);
            s = s * fac + w;
            rlo.x = rlo.x * fac + w * xl.x;
            rlo.y = rlo.y * fac + w * xl.y;
            rlo.z = rlo.z * fac + w * xl.z;
            rlo.w = rlo.w * fac + w * xl.w;
            rhi.x = rhi.x * fac + w * xh.x;
            rhi.y = rhi.y * fac + w * xh.y;
            rhi.z = rhi.z * fac + w * xh.z;
            rhi.w = rhi.w * fac + w * xh.w;
            m = nm;

            xl = nl; xh = nh;
        }
    }

    // merge 16 group partials in LDS
    __shared__ float m_sh[16];
    __shared__ float s_sh[16];
    __shared__ float r_sh[16][128];

    *(float4*)&r_sh[g16][c0] = rlo;
    *(float4*)&r_sh[g16][64 + c0] = rhi;
    if (sl == 0) {
        m_sh[g16] = m;
        s_sh[g16] = s;
    }
    __syncthreads();

    if (tid < 128) {
        int d = tid;
        float Mf = -1e30f;
#pragma unroll
        for (int p = 0; p < 16; ++p) Mf = fmaxf(Mf, m_sh[p]);
        float Sf = 0.0f, Rf = 0.0f;
#pragma unroll
        for (int p = 0; p < 16; ++p) {
            float fac = __expf(m_sh[p] - Mf);   // empty group: exp(-inf-ish)=0
            Sf += s_sh[p] * fac;
            Rf += r_sh[p][d] * fac;
        }
        float* P = &partials[(size_t)(b * SPLIT + sp) * PSTRIDE];
        if (d == 0) { P[0] = Mf; P[1] = Sf; }
        P[4 + d] = Rf;
    }
}

// ---------------- attention pass 2: merge SPLIT partials ----------------------
__launch_bounds__(128)
__global__ void att_merge_kernel(const float* __restrict__ partials,
                                 const float* __restrict__ h,
                                 float* __restrict__ q_star) {
    const int b = blockIdx.x;
    const int d = threadIdx.x;
    const float* P = &partials[(size_t)b * SPLIT * PSTRIDE];
    float M = -1e30f;
#pragma unroll
    for (int p = 0; p < SPLIT; ++p) M = fmaxf(M, P[p * PSTRIDE]);
    float S = 0.0f, R = 0.0f;
#pragma unroll
    for (int p = 0; p < SPLIT; ++p) {
        float fac = __expf(P[p * PSTRIDE] - M);   // empty chunk: exp(-inf)=0
        S += P[p * PSTRIDE + 1] * fac;
        R += P[p * PSTRIDE + 4 + d] * fac;
    }
    q_star[b * 256 + d] = h[b * 128 + d];
    q_star[b * 256 + 128 + d] = R / (S + 1e-16f);
}

// ---------------- launch ------------------------------------------------------
extern "C" void kernel_launch(void* const* d_in, const int* in_sizes, int n_in,
                              void* d_out, int out_size, void* d_ws, size_t ws_size,
                              hipStream_t stream) {
    const float* x    = (const float*)d_in[0];
    const int*   bidx = (const int*)d_in[1];
    const float* W_ih = (const float*)d_in[2];
    const float* W_hh = (const float*)d_in[3];
    const float* b_ih = (const float*)d_in[4];
    const float* b_hh = (const float*)d_in[5];
    float* q_star = (float*)d_out;   // [B, 2D] — doubles as the output

    char* ws = (char*)d_ws;
    float* WT       = (float*)(ws);                 // 384*512*4 = 786432 B
    float* bias     = (float*)(ws + 786432);        // 2048 B
    float* h        = (float*)(ws + 788480);        // 1024*128*4 = 524288 B
    float* c        = (float*)(ws + 1312768);       // 524288 B
    int*   start    = (int*)  (ws + 1837056);       // (B+1)*4 = 4100 B
    float* partials = (float*)(ws + 1841408);       // 1024*8*132*4 = 4325376 B

    hipMemsetAsync(h, 0, BB * DD * sizeof(float), stream);
    hipMemsetAsync(c, 0, BB * DD * sizeof(float), stream);
    hipMemsetAsync(q_star, 0, BB * 2 * DD * sizeof(float), stream);

    prep_kernel<<<(384 * 512 + 255) / 256, 256, 0, stream>>>(W_ih, W_hh, b_ih, b_hh, WT, bias);
    segstart_kernel<<<(NN + 255) / 256, 256, 0, stream>>>(bidx, start);

    for (int step = 0; step < STEPS; ++step) {
        lstm_kernel<<<256, 256, 0, stream>>>(q_star, h, c, WT, bias);
        att_partial_kernel<<<BB * SPLIT, 256, 0, stream>>>(x, h, start, partials);
        att_merge_kernel<<<BB, 128, 0, stream>>>(partials, h, q_star);
    }
}